// Round 1
// baseline (124.789 us; speedup 1.0000x reference)
//
#include <hip/hip_runtime.h>
#include <hip/hip_bf16.h>
#include <math.h>

// Problem constants (fixed by setup_inputs)
constexpr int N  = 64;
constexpr int C  = 128;
constexpr int T  = 256;
constexpr int V  = 25;
constexpr int K  = 3;
constexpr int CT = C * T;          // 32768
constexpr int VK = 12;             // int(0.5 * 25)
constexpr int SPLIT = 16;          // score-pass split along ct per sample

// ---------------- ws layout (bytes) ----------------
// partial dots : N*SPLIT*V floats   = 25600 floats @ 0
// inv_norm     : 1 float            @ 102400
// y_hat        : N*VK floats (768)  @ 102464
// idx          : N*VK ints  (768)   @ 105536
// total ~108.6 KB

// Kernel 1: inv_norm = 1/sqrt(sum(p^2))
__global__ void k_pnorm(const float* __restrict__ p, float* __restrict__ invnorm) {
    float a = 0.f;
    for (int i = threadIdx.x; i < CT; i += blockDim.x) {
        float v = p[i];
        a += v * v;
    }
    #pragma unroll
    for (int off = 32; off > 0; off >>= 1) a += __shfl_down(a, off);
    __shared__ float red[4];
    int lane = threadIdx.x & 63, wid = threadIdx.x >> 6;
    if (lane == 0) red[wid] = a;
    __syncthreads();
    if (threadIdx.x == 0) {
        float s = red[0] + red[1] + red[2] + red[3];
        invnorm[0] = 1.0f / sqrtf(s);
    }
}

// Kernel 2: partial raw dots  partial[(n*SPLIT+s)*V + v] = sum over ct-slice of x[n,ct,v]*p[ct]
__global__ void k_scores(const float* __restrict__ x, const float* __restrict__ p,
                         float* __restrict__ partial) {
    const int n = blockIdx.x / SPLIT;
    const int s = blockIdx.x % SPLIT;
    constexpr int CHUNK = CT / SPLIT;   // 2048
    const int ct0 = s * CHUNK;
    const float* xn = x + (size_t)n * CT * V;

    float acc[V];
    #pragma unroll
    for (int v = 0; v < V; ++v) acc[v] = 0.f;

    for (int ct = ct0 + threadIdx.x; ct < ct0 + CHUNK; ct += blockDim.x) {
        const float pv = p[ct];
        const float* row = xn + (size_t)ct * V;
        #pragma unroll
        for (int v = 0; v < V; ++v) acc[v] += row[v] * pv;
    }

    // wave-level reduce each of the 25 accumulators
    #pragma unroll
    for (int v = 0; v < V; ++v) {
        float a = acc[v];
        #pragma unroll
        for (int off = 32; off > 0; off >>= 1) a += __shfl_down(a, off);
        acc[v] = a;
    }
    __shared__ float red[4][V];
    const int lane = threadIdx.x & 63, wid = threadIdx.x >> 6;
    if (lane == 0) {
        #pragma unroll
        for (int v = 0; v < V; ++v) red[wid][v] = acc[v];
    }
    __syncthreads();
    if (threadIdx.x < V) {
        const int v = threadIdx.x;
        partial[(blockIdx.x) * V + v] = red[0][v] + red[1][v] + red[2][v] + red[3][v];
    }
}

// Kernel 3: per-sample top-12 (stable desc), y_hat=sigmoid, and A_out directly:
// A_out[n,k,a,b] = sum_m A[n,k,idx_a,m]*A[n,k,m,idx_b]
__global__ void k_topk_aout(const float* __restrict__ partial, const float* __restrict__ invnorm,
                            const float* __restrict__ A,
                            int* __restrict__ idxbuf, float* __restrict__ yhatbuf,
                            float* __restrict__ aout) {
    const int n = blockIdx.x;
    __shared__ float ys[V];
    __shared__ int   sidx[VK];
    __shared__ float syh[VK];

    if (threadIdx.x < V) {
        float s = 0.f;
        #pragma unroll
        for (int k = 0; k < SPLIT; ++k) s += partial[(n * SPLIT + k) * V + threadIdx.x];
        ys[threadIdx.x] = s * invnorm[0];
    }
    __syncthreads();

    if (threadIdx.x < V) {
        const int v = threadIdx.x;
        const float my = ys[v];
        int rank = 0;
        for (int u = 0; u < V; ++u) {
            const float yu = ys[u];
            if (yu > my || (yu == my && u < v)) ++rank;
        }
        if (rank < VK) {
            sidx[rank] = v;
            const float yh = 1.0f / (1.0f + expf(-my));
            syh[rank] = yh;
            idxbuf[n * VK + rank]  = v;
            yhatbuf[n * VK + rank] = yh;
        }
    }
    __syncthreads();

    const float* An = A + (size_t)n * K * V * V;
    for (int o = threadIdx.x; o < K * VK * VK; o += blockDim.x) {
        const int k = o / (VK * VK);
        const int r = o % (VK * VK);
        const int a = r / VK, b = r % VK;
        const int ia = sidx[a], ib = sidx[b];
        const float* Ak = An + (size_t)k * V * V;
        float ssum = 0.f;
        #pragma unroll
        for (int m = 0; m < V; ++m) ssum += Ak[ia * V + m] * Ak[m * V + ib];
        aout[((size_t)n * K + k) * VK * VK + r] = ssum;
    }
}

// Kernel 4: gather + scale.  x_out[n,ct,j] = x[n,ct,idx[n,j]] * y_hat[n,j]
// one thread per (n, ct); 48-byte output rows are 16B aligned -> 3x float4 stores
__global__ void k_gather(const float* __restrict__ x, const int* __restrict__ idxbuf,
                         const float* __restrict__ yhatbuf, float* __restrict__ xout) {
    const int b  = blockIdx.x;          // N * (CT/256) = 8192 blocks
    const int n  = b >> 7;              // /128
    const int ct = ((b & 127) << 8) + threadIdx.x;

    __shared__ int   sidx[VK];
    __shared__ float syh[VK];
    if (threadIdx.x < VK) {
        sidx[threadIdx.x] = idxbuf[n * VK + threadIdx.x];
        syh[threadIdx.x]  = yhatbuf[n * VK + threadIdx.x];
    }
    __syncthreads();

    const float* row = x + ((size_t)n * CT + ct) * V;
    float o[VK];
    #pragma unroll
    for (int j = 0; j < VK; ++j) o[j] = row[sidx[j]] * syh[j];

    float4* dst = (float4*)(xout + ((size_t)n * CT + ct) * VK);
    dst[0] = make_float4(o[0], o[1], o[2],  o[3]);
    dst[1] = make_float4(o[4], o[5], o[6],  o[7]);
    dst[2] = make_float4(o[8], o[9], o[10], o[11]);
}

extern "C" void kernel_launch(void* const* d_in, const int* in_sizes, int n_in,
                              void* d_out, int out_size, void* d_ws, size_t ws_size,
                              hipStream_t stream) {
    const float* x = (const float*)d_in[0];
    const float* A = (const float*)d_in[1];
    const float* p = (const float*)d_in[2];

    float* xout = (float*)d_out;                       // N*CT*VK floats
    float* aout = xout + (size_t)N * CT * VK;          // N*K*VK*VK floats

    char* ws = (char*)d_ws;
    float* partial = (float*)(ws);                     // 25600 floats
    float* invnorm = (float*)(ws + 102400);            // 1 float
    float* yhatbuf = (float*)(ws + 102464);            // 768 floats
    int*   idxbuf  = (int*)  (ws + 105536);            // 768 ints

    k_pnorm<<<1, 256, 0, stream>>>(p, invnorm);
    k_scores<<<N * SPLIT, 256, 0, stream>>>(x, p, partial);
    k_topk_aout<<<N, 256, 0, stream>>>(partial, invnorm, A, idxbuf, yhatbuf, aout);
    k_gather<<<N * (CT / 256), 256, 0, stream>>>(x, idxbuf, yhatbuf, xout);
}

// Round 2
// 115.925 us; speedup vs baseline: 1.0765x; 1.0765x over previous
//
#include <hip/hip_runtime.h>
#include <hip/hip_bf16.h>
#include <math.h>

// Problem constants (fixed by setup_inputs)
constexpr int N  = 64;
constexpr int C  = 128;
constexpr int T  = 256;
constexpr int V  = 25;
constexpr int K  = 3;
constexpr int CT = C * T;          // 32768
constexpr int VK = 12;             // int(0.5 * 25)
constexpr int SPLIT = 32;          // score-pass split along ct per sample
constexpr int ROWS  = 256;         // rows staged per LDS tile

// ---------------- ws layout (bytes) ----------------
// partial dots : N*SPLIT*V floats = 51200 floats @ 0        (204800 B)
// p2 partials  : SPLIT floats               @ 204800        (128 B)
// y_hat        : N*VK floats (768)          @ 204928        (3072 B)
// idx          : N*VK ints  (768)           @ 208000        (3072 B)
// total ~211 KB

// Kernel 1: partial raw dots, LDS-staged coalesced.
// partial[(n*SPLIT+s)*V + v] = sum over ct-slice of x[n,ct,v]*p[ct]
// n==0 blocks also write p2partial[s] = sum of p^2 over their ct-slice.
__global__ void k_scores(const float* __restrict__ x, const float* __restrict__ p,
                         float* __restrict__ partial, float* __restrict__ p2partial) {
    const int n = blockIdx.x / SPLIT;
    const int s = blockIdx.x % SPLIT;
    constexpr int CHUNK = CT / SPLIT;     // 1024
    constexpr int TILES = CHUNK / ROWS;   // 4
    const int ct0 = s * CHUNK;
    const float* xn = x + (size_t)n * CT * V;

    __shared__ float lds[ROWS * V];       // 6400 floats = 25600 B

    float acc[V];
    #pragma unroll
    for (int v = 0; v < V; ++v) acc[v] = 0.f;
    float psq = 0.f;

    for (int tile = 0; tile < TILES; ++tile) {
        const int base = ct0 + tile * ROWS;
        // coalesced float4 staging: 1600 float4s
        const float4* src = (const float4*)(xn + (size_t)base * V);
        float4* dstl = (float4*)lds;
        constexpr int NV4 = ROWS * V / 4; // 1600
        for (int i = threadIdx.x; i < NV4; i += 256) dstl[i] = src[i];
        __syncthreads();

        const int ct = base + threadIdx.x;
        const float pv = p[ct];
        psq += pv * pv;
        const float* row = lds + threadIdx.x * V;   // stride 25: bank-conflict-free
        #pragma unroll
        for (int v = 0; v < V; ++v) acc[v] += row[v] * pv;
        __syncthreads();
    }

    // wave-level reduce each of the 25 accumulators + psq
    #pragma unroll
    for (int v = 0; v < V; ++v) {
        float a = acc[v];
        #pragma unroll
        for (int off = 32; off > 0; off >>= 1) a += __shfl_down(a, off);
        acc[v] = a;
    }
    #pragma unroll
    for (int off = 32; off > 0; off >>= 1) psq += __shfl_down(psq, off);

    __shared__ float red[4][V];
    __shared__ float redp[4];
    const int lane = threadIdx.x & 63, wid = threadIdx.x >> 6;
    if (lane == 0) {
        #pragma unroll
        for (int v = 0; v < V; ++v) red[wid][v] = acc[v];
        redp[wid] = psq;
    }
    __syncthreads();
    if (threadIdx.x < V) {
        const int v = threadIdx.x;
        partial[(size_t)blockIdx.x * V + v] = red[0][v] + red[1][v] + red[2][v] + red[3][v];
    }
    if (threadIdx.x == V && n == 0) {
        p2partial[s] = redp[0] + redp[1] + redp[2] + redp[3];
    }
}

// Kernel 2: per-sample top-12 (stable desc), y_hat=sigmoid, and A_out directly:
// A_out[n,k,a,b] = sum_m A[n,k,idx_a,m]*A[n,k,m,idx_b]
__global__ void k_topk_aout(const float* __restrict__ partial, const float* __restrict__ p2partial,
                            const float* __restrict__ A,
                            int* __restrict__ idxbuf, float* __restrict__ yhatbuf,
                            float* __restrict__ aout) {
    const int n = blockIdx.x;
    __shared__ float ys[V];
    __shared__ int   sidx[VK];
    __shared__ float s_inv;

    if (threadIdx.x == 0) {
        float s = 0.f;
        #pragma unroll
        for (int i = 0; i < SPLIT; ++i) s += p2partial[i];
        s_inv = rsqrtf(s);
    }
    __syncthreads();

    if (threadIdx.x < V) {
        float s = 0.f;
        #pragma unroll
        for (int k = 0; k < SPLIT; ++k) s += partial[((size_t)n * SPLIT + k) * V + threadIdx.x];
        ys[threadIdx.x] = s * s_inv;
    }
    __syncthreads();

    if (threadIdx.x < V) {
        const int v = threadIdx.x;
        const float my = ys[v];
        int rank = 0;
        for (int u = 0; u < V; ++u) {
            const float yu = ys[u];
            if (yu > my || (yu == my && u < v)) ++rank;
        }
        if (rank < VK) {
            sidx[rank] = v;
            const float yh = 1.0f / (1.0f + expf(-my));
            idxbuf[n * VK + rank]  = v;
            yhatbuf[n * VK + rank] = yh;
        }
    }
    __syncthreads();

    const float* An = A + (size_t)n * K * V * V;
    for (int o = threadIdx.x; o < K * VK * VK; o += blockDim.x) {
        const int k = o / (VK * VK);
        const int r = o % (VK * VK);
        const int a = r / VK, b = r % VK;
        const int ia = sidx[a], ib = sidx[b];
        const float* Ak = An + (size_t)k * V * V;
        float ssum = 0.f;
        #pragma unroll
        for (int m = 0; m < V; ++m) ssum += Ak[ia * V + m] * Ak[m * V + ib];
        aout[((size_t)n * K + k) * VK * VK + r] = ssum;
    }
}

// Kernel 3: gather + scale, LDS-staged.  x_out[n,ct,j] = x[n,ct,idx[n,j]] * y_hat[n,j]
__global__ void k_gather(const float* __restrict__ x, const int* __restrict__ idxbuf,
                         const float* __restrict__ yhatbuf, float* __restrict__ xout) {
    const int b  = blockIdx.x;          // N * (CT/256) = 8192 blocks
    const int n  = b >> 7;              // /128
    const int r0 = (b & 127) << 8;      // row base within sample

    __shared__ float lds[ROWS * V];     // 25600 B
    __shared__ int   sidx[VK];
    __shared__ float syh[VK];
    if (threadIdx.x < VK) {
        sidx[threadIdx.x] = idxbuf[n * VK + threadIdx.x];
        syh[threadIdx.x]  = yhatbuf[n * VK + threadIdx.x];
    }

    // coalesced float4 staging of 256 rows
    const float4* src = (const float4*)(x + ((size_t)n * CT + r0) * V);
    float4* dstl = (float4*)lds;
    constexpr int NV4 = ROWS * V / 4;   // 1600
    for (int i = threadIdx.x; i < NV4; i += 256) dstl[i] = src[i];
    __syncthreads();

    const float* row = lds + threadIdx.x * V;   // stride 25: conflict-free
    float o[VK];
    #pragma unroll
    for (int j = 0; j < VK; ++j) o[j] = row[sidx[j]] * syh[j];

    float4* dst = (float4*)(xout + ((size_t)n * CT + r0 + threadIdx.x) * VK);
    dst[0] = make_float4(o[0], o[1], o[2],  o[3]);
    dst[1] = make_float4(o[4], o[5], o[6],  o[7]);
    dst[2] = make_float4(o[8], o[9], o[10], o[11]);
}

extern "C" void kernel_launch(void* const* d_in, const int* in_sizes, int n_in,
                              void* d_out, int out_size, void* d_ws, size_t ws_size,
                              hipStream_t stream) {
    const float* x = (const float*)d_in[0];
    const float* A = (const float*)d_in[1];
    const float* p = (const float*)d_in[2];

    float* xout = (float*)d_out;                       // N*CT*VK floats
    float* aout = xout + (size_t)N * CT * VK;          // N*K*VK*VK floats

    char* ws = (char*)d_ws;
    float* partial   = (float*)(ws);                   // 51200 floats
    float* p2partial = (float*)(ws + 204800);          // 32 floats
    float* yhatbuf   = (float*)(ws + 204928);          // 768 floats
    int*   idxbuf    = (int*)  (ws + 208000);          // 768 ints

    k_scores<<<N * SPLIT, 256, 0, stream>>>(x, p, partial, p2partial);
    k_topk_aout<<<N, 256, 0, stream>>>(partial, p2partial, A, idxbuf, yhatbuf, aout);
    k_gather<<<N * (CT / 256), 256, 0, stream>>>(x, idxbuf, yhatbuf, xout);
}

// Round 3
// 92.315 us; speedup vs baseline: 1.3518x; 1.2557x over previous
//
#include <hip/hip_runtime.h>
#include <hip/hip_bf16.h>
#include <math.h>

// Problem constants (fixed by setup_inputs)
constexpr int N  = 64;
constexpr int V  = 25;
constexpr int K  = 3;
constexpr int CT = 32768;          // C*T
constexpr int VK = 12;             // int(0.5 * 25)
constexpr int SPLIT = 32;          // score-pass split along ct per sample
constexpr int ROWS  = 256;         // rows staged per LDS tile
constexpr int NF4   = ROWS * V / 4;  // 1600 float4s per tile

// ---------------- ws layout (bytes) ----------------
// partial dots : N*SPLIT*V floats = 51200 floats @ 0        (204800 B)
// p2 partials  : SPLIT floats               @ 204800        (128 B)
// y_hat        : N*VK floats (768)          @ 204928        (3072 B)
// idx          : N*VK ints  (768)           @ 208000        (3072 B)

__device__ __forceinline__ void gload_lds16(const float* g, float* l) {
    // async global->LDS DMA, 16B per lane; LDS dest = wave-uniform base + lane*16
    __builtin_amdgcn_global_load_lds(
        (const __attribute__((address_space(1))) void*)g,
        (__attribute__((address_space(3))) void*)l, 16, 0, 0);
}

// stage NF4 float4s from gsrc into lds; each wave owns contiguous 64-chunk ranges
__device__ __forceinline__ void stage_tile(const float* __restrict__ gsrc, float* lds, int tid) {
    const int wave = tid >> 6, lane = tid & 63;
    for (int b = wave * 64; b < NF4; b += 256) {          // 1600 = 6*256 + 64 (wave0 takes the tail)
        gload_lds16(gsrc + (size_t)(b + lane) * 4, lds + (size_t)b * 4);
    }
}

// Kernel 1: partial raw dots, LDS-staged via global_load_lds.
// partial[(n*SPLIT+s)*V + v] = sum over ct-slice of x[n,ct,v]*p[ct]
// n==0 blocks also write p2partial[s] = sum of p^2 over their ct-slice.
__global__ __launch_bounds__(256) void k_scores(const float* __restrict__ x, const float* __restrict__ p,
                         float* __restrict__ partial, float* __restrict__ p2partial) {
    const int n = blockIdx.x / SPLIT;
    const int s = blockIdx.x % SPLIT;
    constexpr int CHUNK = CT / SPLIT;     // 1024
    constexpr int TILES = CHUNK / ROWS;   // 4
    const int ct0 = s * CHUNK;
    const float* xn = x + (size_t)n * CT * V;
    const int tid = threadIdx.x;

    __shared__ float lds[ROWS * V];       // 25600 B

    float acc[V];
    #pragma unroll
    for (int v = 0; v < V; ++v) acc[v] = 0.f;
    float psq = 0.f;

    for (int tile = 0; tile < TILES; ++tile) {
        const int base_ct = ct0 + tile * ROWS;
        stage_tile(xn + (size_t)base_ct * V, lds, tid);
        asm volatile("s_waitcnt vmcnt(0)" ::: "memory");
        __syncthreads();

        const float pv = p[base_ct + tid];
        psq += pv * pv;
        const float* row = lds + tid * V;   // stride 25: bank-conflict-free
        #pragma unroll
        for (int v = 0; v < V; ++v) acc[v] += row[v] * pv;
        __syncthreads();
    }

    #pragma unroll
    for (int v = 0; v < V; ++v) {
        float a = acc[v];
        #pragma unroll
        for (int off = 32; off > 0; off >>= 1) a += __shfl_down(a, off);
        acc[v] = a;
    }
    #pragma unroll
    for (int off = 32; off > 0; off >>= 1) psq += __shfl_down(psq, off);

    __shared__ float red[4][V];
    __shared__ float redp[4];
    const int lane = tid & 63, wid = tid >> 6;
    if (lane == 0) {
        #pragma unroll
        for (int v = 0; v < V; ++v) red[wid][v] = acc[v];
        redp[wid] = psq;
    }
    __syncthreads();
    if (tid < V) {
        partial[(size_t)blockIdx.x * V + tid] = red[0][tid] + red[1][tid] + red[2][tid] + red[3][tid];
    }
    if (tid == V && n == 0) {
        p2partial[s] = redp[0] + redp[1] + redp[2] + redp[3];
    }
}

// Kernel 2: per-sample top-12 (stable desc on RAW sums — monotone-equivalent to
// normalized ranking), y_hat = sigmoid(normalized score). 64 blocks x 64 threads.
__global__ __launch_bounds__(64) void k_topk(const float* __restrict__ partial,
                       const float* __restrict__ p2partial,
                       int* __restrict__ idxbuf, float* __restrict__ yhatbuf) {
    const int n = blockIdx.x;
    __shared__ float ys[V];
    if (threadIdx.x < V) {
        float s = 0.f;
        #pragma unroll
        for (int kk = 0; kk < SPLIT; ++kk) s += partial[((size_t)n * SPLIT + kk) * V + threadIdx.x];
        ys[threadIdx.x] = s;
    }
    __syncthreads();
    if (threadIdx.x < V) {
        const int v = threadIdx.x;
        float s2 = 0.f;
        #pragma unroll
        for (int i = 0; i < SPLIT; ++i) s2 += p2partial[i];
        const float my = ys[v];
        int rank = 0;
        for (int u = 0; u < V; ++u) {
            const float yu = ys[u];
            if (yu > my || (yu == my && u < v)) ++rank;
        }
        if (rank < VK) {
            idxbuf[n * VK + rank]  = v;
            yhatbuf[n * VK + rank] = 1.0f / (1.0f + expf(-my * rsqrtf(s2)));
        }
    }
}

// Kernel 3: blocks [0,8192): gather+scale with fully-coalesced stores.
//           blocks [8192,8384): A_out[n,k,a,b] = sum_m A[n,k,ia,m]*A[n,k,m,ib]
__global__ __launch_bounds__(256) void k_gather_aout(const float* __restrict__ x, const float* __restrict__ A,
                             const int* __restrict__ idxbuf, const float* __restrict__ yhatbuf,
                             float* __restrict__ xout, float* __restrict__ aout) {
    __shared__ float lds[ROWS * V];     // 25600 B (aout path uses first 2500 B)
    __shared__ int   sidx[VK];
    __shared__ float syh[VK];
    const int tid = threadIdx.x;

    if (blockIdx.x < (unsigned)(N * (CT / ROWS))) {        // 8192 gather blocks
        const int b  = blockIdx.x;
        const int n  = b >> 7;              // /128 tiles per sample
        const int r0 = (b & 127) << 8;      // row base within sample
        if (tid < VK) {
            sidx[tid] = idxbuf[n * VK + tid];
            syh[tid]  = yhatbuf[n * VK + tid];
        }
        stage_tile(x + ((size_t)n * CT + r0) * V, lds, tid);
        asm volatile("s_waitcnt vmcnt(0)" ::: "memory");
        __syncthreads();

        // out tile = 256 rows x 12 floats = 768 float4s; thread t writes f = t, t+256, t+512
        float4* dst = (float4*)(xout + ((size_t)n * CT + r0) * VK);
        #pragma unroll
        for (int j = 0; j < 3; ++j) {
            const int f   = tid + j * 256;
            const int row = f / 3;
            const int c0  = (f % 3) * 4;
            float4 o;
            o.x = lds[row * V + sidx[c0 + 0]] * syh[c0 + 0];
            o.y = lds[row * V + sidx[c0 + 1]] * syh[c0 + 1];
            o.z = lds[row * V + sidx[c0 + 2]] * syh[c0 + 2];
            o.w = lds[row * V + sidx[c0 + 3]] * syh[c0 + 3];
            dst[f] = o;                      // contiguous across lanes: coalesced
        }
    } else {
        const int b2 = blockIdx.x - N * (CT / ROWS);   // [0, 192)
        const int n  = b2 / K;
        const int k  = b2 % K;
        if (tid < VK) sidx[tid] = idxbuf[n * VK + tid];
        const float* Ak = A + ((size_t)n * K + k) * V * V;
        for (int i = tid; i < V * V; i += 256) lds[i] = Ak[i];
        __syncthreads();
        if (tid < VK * VK) {
            const int a  = tid / VK, bc = tid % VK;
            const int ia = sidx[a], ib = sidx[bc];
            float ssum = 0.f;
            #pragma unroll
            for (int m = 0; m < V; ++m) ssum += lds[ia * V + m] * lds[m * V + ib];
            aout[((size_t)n * K + k) * VK * VK + tid] = ssum;
        }
    }
}

extern "C" void kernel_launch(void* const* d_in, const int* in_sizes, int n_in,
                              void* d_out, int out_size, void* d_ws, size_t ws_size,
                              hipStream_t stream) {
    const float* x = (const float*)d_in[0];
    const float* A = (const float*)d_in[1];
    const float* p = (const float*)d_in[2];

    float* xout = (float*)d_out;                       // N*CT*VK floats
    float* aout = xout + (size_t)N * CT * VK;          // N*K*VK*VK floats

    char* ws = (char*)d_ws;
    float* partial   = (float*)(ws);                   // 51200 floats
    float* p2partial = (float*)(ws + 204800);          // 32 floats
    float* yhatbuf   = (float*)(ws + 204928);          // 768 floats
    int*   idxbuf    = (int*)  (ws + 208000);          // 768 ints

    k_scores<<<N * SPLIT, 256, 0, stream>>>(x, p, partial, p2partial);
    k_topk<<<N, 64, 0, stream>>>(partial, p2partial, idxbuf, yhatbuf);
    k_gather_aout<<<N * (CT / ROWS) + N * K, 256, 0, stream>>>(x, A, idxbuf, yhatbuf, xout, aout);
}